// Round 15
// baseline (54.891 us; speedup 1.0000x reference)
//
#include <hip/hip_runtime.h>

#define BSZ 32
#define NN 512
#define INF 256
#define NH 4
#define HD 512
#define NEG_SLOPE 0.2f

typedef __attribute__((ext_vector_type(8))) short bf16x8;
typedef __attribute__((ext_vector_type(8))) unsigned short ushort8;
typedef __attribute__((ext_vector_type(4))) float f32x4;

static __device__ __forceinline__ unsigned short f2bf(float f) {
    unsigned u = __builtin_bit_cast(unsigned, f);
    return (unsigned short)((u + 0x7FFFu + ((u >> 16) & 1u)) >> 16);
}

static __device__ __forceinline__ bf16x8 pk8(float4 a, float4 b) {
    unsigned d0, d1, d2, d3;
    asm("v_cvt_pk_bf16_f32 %0, %1, %2" : "=v"(d0) : "v"(a.x), "v"(a.y));
    asm("v_cvt_pk_bf16_f32 %0, %1, %2" : "=v"(d1) : "v"(a.z), "v"(a.w));
    asm("v_cvt_pk_bf16_f32 %0, %1, %2" : "=v"(d2) : "v"(b.x), "v"(b.y));
    asm("v_cvt_pk_bf16_f32 %0, %1, %2" : "=v"(d3) : "v"(b.z), "v"(b.w));
    uint4 u; u.x = d0; u.y = d1; u.z = d2; u.w = d3;
    return __builtin_bit_cast(bf16x8, u);
}

static __device__ __forceinline__ void gl_lds16(const void* g, void* l) {
    __builtin_amdgcn_global_load_lds(
        (const __attribute__((address_space(1))) unsigned int*)g,
        (__attribute__((address_space(3))) unsigned int*)l, 16, 0, 0);
}

// ================= single kernel, NO grid-wide sync =================
// Per batch b (32 blocks, all on XCD b>>2):
//   sub in [16,32): pack wB slice -> wcnt++; build 32 mask rows -> bcnt[b]++
//   sub in [0,16):  spin wcnt==512; 32-row proj; fence; bcnt[b]++
//   all:            spin bcnt[b]==32; fence; attention for (b,h,i0)
__global__ __launch_bounds__(256, 4) void mega2(
    const float* __restrict__ x, const float* __restrict__ adj,
    const float* __restrict__ w, const float* __restrict__ ai,
    const float* __restrict__ aj, const float* __restrict__ bias,
    float* __restrict__ out, unsigned short* __restrict__ wB,
    unsigned short* __restrict__ hB, float* __restrict__ ciT,
    float* __restrict__ cjT, unsigned char* __restrict__ mbB,
    unsigned* __restrict__ flags)
{
    __shared__ __align__(16) char smem[32768];
    const int tid = threadIdx.x;
    const int lane = tid & 63, wave = tid >> 6;
    const int l15 = lane & 15, g = lane >> 4;

    const int orig = blockIdx.x;
    const int swz = (orig & 7) * 128 + (orig >> 3);    // bijective, XCD-chunked
    const int b   = swz >> 5;
    const int sub = swz & 31;

    if (sub >= 16) {
        // ---- wB slice pack (1 KB): slice s = b*16 + (sub-16) ----
        {
            int s = b * 16 + (sub - 16);
            int gid = s * 256 + tid;
            int c = gid & 511, k = gid >> 9;
            int kb = k >> 5, gg = (k >> 3) & 3, e = k & 7;
            wB[(((size_t)(kb * 4 + gg) * 512) + c) * 8 + e] =
                f2bf(w[(size_t)k * 512 + c]);
        }
        __syncthreads();
        __threadfence();
        if (tid == 0)
            __hip_atomic_fetch_add(&flags[32], 1u, __ATOMIC_RELEASE,
                                   __HIP_MEMORY_SCOPE_AGENT);
        // ---- maskbytes for rows b*512 + (sub-16)*32 .. +32 ----
        {
            const int r0 = b * NN + (sub - 16) * 32 + wave * 8;
            #pragma unroll
            for (int rr = 0; rr < 8; ++rr) {
                const float* ap = adj + (size_t)(r0 + rr) * NN + lane * 8;
                float4 a0 = *(const float4*)ap;
                float4 a1 = *(const float4*)(ap + 4);
                unsigned byte = 0;
                byte |= (a0.x > 0.f) ? 1u : 0u;  byte |= (a0.y > 0.f) ? 2u : 0u;
                byte |= (a0.z > 0.f) ? 4u : 0u;  byte |= (a0.w > 0.f) ? 8u : 0u;
                byte |= (a1.x > 0.f) ? 16u : 0u; byte |= (a1.y > 0.f) ? 32u : 0u;
                byte |= (a1.z > 0.f) ? 64u : 0u; byte |= (a1.w > 0.f) ? 128u : 0u;
                mbB[(size_t)(r0 + rr) * 64 + lane] = (unsigned char)byte;
            }
        }
        __syncthreads();
        __threadfence();
        if (tid == 0)
            __hip_atomic_fetch_add(&flags[b], 1u, __ATOMIC_RELEASE,
                                   __HIP_MEMORY_SCOPE_AGENT);
    } else {
        // ---- projection: rows b*512 + sub*32 .. +32 ----
        if (tid == 0) {
            while (__hip_atomic_load(&flags[32], __ATOMIC_ACQUIRE,
                                     __HIP_MEMORY_SCOPE_AGENT) < 512u)
                __builtin_amdgcn_s_sleep(2);
        }
        __syncthreads();
        __threadfence();

        unsigned short* hs = (unsigned short*)smem;    // 32 KB slab image
        const int head = wave;
        const int nloc0 = sub * 32;
        const int row0 = b * NN + nloc0;
        const int kb2 = sub;

        f32x4 acc[2][8] = {};
        const float* xp0 = x + (size_t)(row0 + l15) * INF + g * 8;
        const float* xp1 = xp0 + 16 * INF;
        const unsigned short* bp = wB + ((size_t)g * 512 + head * 128 + l15) * 8;

        #pragma unroll
        for (int kb = 0; kb < 8; ++kb) {
            float4 f0 = *(const float4*)(xp0 + kb * 32);
            float4 f1 = *(const float4*)(xp0 + kb * 32 + 4);
            float4 f2 = *(const float4*)(xp1 + kb * 32);
            float4 f3 = *(const float4*)(xp1 + kb * 32 + 4);
            bf16x8 a0 = pk8(f0, f1);
            bf16x8 a1 = pk8(f2, f3);
            #pragma unroll
            for (int nf = 0; nf < 8; ++nf) {
                bf16x8 bv = *(const bf16x8*)(bp + (size_t)kb * 16384 + nf * 128);
                acc[0][nf] = __builtin_amdgcn_mfma_f32_16x16x32_bf16(a0, bv, acc[0][nf], 0, 0, 0);
                acc[1][nf] = __builtin_amdgcn_mfma_f32_16x16x32_bf16(a1, bv, acc[1][nf], 0, 0, 0);
            }
        }

        float aiv[8], ajv[8];
        #pragma unroll
        for (int nf = 0; nf < 8; ++nf) {
            aiv[nf] = ai[head * 128 + nf * 16 + l15];
            ajv[nf] = aj[head * 128 + nf * 16 + l15];
        }

        #pragma unroll
        for (int m = 0; m < 2; ++m) {
            float pi[4] = {0,0,0,0}, pj[4] = {0,0,0,0};
            #pragma unroll
            for (int nf = 0; nf < 8; ++nf)
                #pragma unroll
                for (int reg = 0; reg < 4; ++reg) {
                    pi[reg] = fmaf(acc[m][nf][reg], aiv[nf], pi[reg]);
                    pj[reg] = fmaf(acc[m][nf][reg], ajv[nf], pj[reg]);
                }
            #pragma unroll
            for (int reg = 0; reg < 4; ++reg) {
                #pragma unroll
                for (int off = 1; off < 16; off <<= 1) {
                    pi[reg] += __shfl_xor(pi[reg], off);
                    pj[reg] += __shfl_xor(pj[reg], off);
                }
            }
            if (l15 == 0) {
                #pragma unroll
                for (int reg = 0; reg < 4; ++reg) {
                    int n = nloc0 + 16 * m + 4 * g + reg;
                    ciT[((size_t)(head * BSZ + b) * NN) + n] = pi[reg];
                    cjT[((size_t)(head * BSZ + b) * NN) + n] = pj[reg];
                }
            }
            #pragma unroll
            for (int reg = 0; reg < 4; ++reg) {
                int jloc = 16 * m + 4 * g + reg;
                int g2 = jloc >> 3, e = jloc & 7;
                #pragma unroll
                for (int nf = 0; nf < 8; ++nf)
                    hs[head * 4096 + nf * 512 + g2 * 128 + l15 * 8 + e] =
                        f2bf(acc[m][nf][reg]);
            }
        }
        __syncthreads();
        {   // linear 8 KB copy per head
            ushort8* dst = (ushort8*)(hB + (((size_t)(b * 4 + head) * 16 + kb2) * 4096));
            const ushort8* src = (const ushort8*)(hs + head * 4096);
            #pragma unroll
            for (int it = 0; it < 8; ++it)
                dst[it * 64 + lane] = src[it * 64 + lane];
        }
        __syncthreads();
        __threadfence();
        if (tid == 0)
            __hip_atomic_fetch_add(&flags[b], 1u, __ATOMIC_RELEASE,
                                   __HIP_MEMORY_SCOPE_AGENT);
    }

    // ---------------- attention for (b, h, i0) ----------------
    if (tid == 0) {
        while (__hip_atomic_load(&flags[b], __ATOMIC_ACQUIRE,
                                 __HIP_MEMORY_SCOPE_AGENT) < 32u)
            __builtin_amdgcn_s_sleep(2);
    }
    __syncthreads();
    __threadfence();

    {
        unsigned short (*Bst)[4096] = (unsigned short(*)[4096])smem;   // 16 KB
        float* cjh  = (float*)(smem + 16384);                          // 2 KB
        float* cih  = (float*)(smem + 18432);                          // 256 B
        unsigned (*maskS)[17] = (unsigned(*)[17])(smem + 18688);       // 4.25 KB
        float* Mpart = (float*)(smem + 23040);
        const unsigned* mb = (const unsigned*)mbB;

        const int h  = (swz >> 3) & 3;
        const int i0 = (swz & 7) * 64;

        const char* gslab = (const char*)(hB + (size_t)(b * NH + h) * 65536);

        gl_lds16(gslab + wave * 2048 + lane * 16,        (char*)&Bst[0][0] + wave * 2048);
        gl_lds16(gslab + wave * 2048 + 1024 + lane * 16, (char*)&Bst[0][0] + wave * 2048 + 1024);

        {
            const float* src = cjT + (size_t)(h * BSZ + b) * NN;
            float v0 = src[tid], v1 = src[tid + 256];
            cjh[tid] = v0; cjh[tid + 256] = v1;
            float mv = fmaxf(v0, v1);
            #pragma unroll
            for (int off = 32; off; off >>= 1) mv = fmaxf(mv, __shfl_xor(mv, off));
            if (lane == 0) Mpart[wave] = mv;
            if (tid < 64) cih[tid] = ciT[(size_t)(h * BSZ + b) * NN + i0 + tid];
            uint4 m4 = ((const uint4*)(mb + ((size_t)b * NN + i0) * 16))[tid];
            int base = tid * 4, row = base >> 4, wi = base & 15;
            maskS[row][wi] = m4.x; maskS[row][wi + 1] = m4.y;
            maskS[row][wi + 2] = m4.z; maskS[row][wi + 3] = m4.w;
        }
        __syncthreads();

        const float M = fmaxf(fmaxf(Mpart[0], Mpart[1]), fmaxf(Mpart[2], Mpart[3]));
        const float bc = cih[wave * 16 + l15];
        float smx = bc + M;
        const float mrow = fmaxf(smx, NEG_SLOPE * smx);

        float bvv[8];
        #pragma unroll
        for (int nf = 0; nf < 8; ++nf) bvv[nf] = bias[h * 128 + nf * 16 + l15];

        bf16x8 ones;
        #pragma unroll
        for (int e = 0; e < 8; ++e) ones[e] = (short)0x3F80;

        f32x4 acc[8] = {};
        f32x4 accs = {};
        int cur = 0;
        const unsigned* mrowp = maskS[wave * 16 + l15];

        for (int kb = 0; kb < 16; ++kb) {
            if (kb < 15) {
                const char* gs = gslab + (size_t)(kb + 1) * 8192 + wave * 2048 + lane * 16;
                char* ld = (char*)&Bst[cur ^ 1][0] + wave * 2048;
                gl_lds16(gs, ld);
                gl_lds16(gs + 1024, ld + 1024);
            }

            float4 cva = *(const float4*)&cjh[kb * 32 + g * 8];
            float4 cvb = *(const float4*)&cjh[kb * 32 + g * 8 + 4];
            float cj8[8] = {cva.x, cva.y, cva.z, cva.w, cvb.x, cvb.y, cvb.z, cvb.w};
            unsigned byte = (mrowp[kb] >> (g * 8)) & 0xFFu;
            float p[8];
            #pragma unroll
            for (int e = 0; e < 8; ++e) {
                float s = bc + cj8[e];
                s = fmaxf(s, NEG_SLOPE * s);
                float pe = __expf(s - mrow);
                p[e] = ((byte >> e) & 1u) ? pe : 0.f;
            }
            unsigned d0, d1, d2, d3;
            asm("v_cvt_pk_bf16_f32 %0, %1, %2" : "=v"(d0) : "v"(p[0]), "v"(p[1]));
            asm("v_cvt_pk_bf16_f32 %0, %1, %2" : "=v"(d1) : "v"(p[2]), "v"(p[3]));
            asm("v_cvt_pk_bf16_f32 %0, %1, %2" : "=v"(d2) : "v"(p[4]), "v"(p[5]));
            asm("v_cvt_pk_bf16_f32 %0, %1, %2" : "=v"(d3) : "v"(p[6]), "v"(p[7]));
            uint4 u; u.x = d0; u.y = d1; u.z = d2; u.w = d3;
            bf16x8 av = __builtin_bit_cast(bf16x8, u);

            const char* bb = (const char*)&Bst[cur][0] + lane * 16;
            bf16x8 bfr[8];
            #pragma unroll
            for (int nf = 0; nf < 8; ++nf)
                bfr[nf] = *(const bf16x8*)(bb + nf * 1024);

            #pragma unroll
            for (int nf = 0; nf < 8; ++nf)
                acc[nf] = __builtin_amdgcn_mfma_f32_16x16x32_bf16(av, bfr[nf], acc[nf], 0, 0, 0);
            accs = __builtin_amdgcn_mfma_f32_16x16x32_bf16(av, ones, accs, 0, 0, 0);

            if (kb < 15) { __syncthreads(); cur ^= 1; }
        }

        #pragma unroll
        for (int reg = 0; reg < 4; ++reg) {
            float sum = accs[reg];
            float inv = sum > 0.f ? 1.f / sum : 0.f;
            const int i = i0 + wave * 16 + g * 4 + reg;
            #pragma unroll
            for (int nf = 0; nf < 8; ++nf) {
                int colg = h * 128 + nf * 16 + l15;
                out[(size_t)(b * NN + i) * HD + colg] = acc[nf][reg] * inv + bvv[nf];
            }
        }
    }
}

// ================= fallback: R13 three-kernel path =================
__global__ __launch_bounds__(256) void k_prep(
    const float* __restrict__ w, unsigned short* __restrict__ wB,
    const float* __restrict__ adj, unsigned char* __restrict__ mbB)
{
    const int bid = blockIdx.x;
    if (bid < 2048) {
        const int lane = threadIdx.x & 63, wave = threadIdx.x >> 6;
        const int row0 = bid * 8 + wave * 2;
        #pragma unroll
        for (int rr = 0; rr < 2; ++rr) {
            const float* ap = adj + (size_t)(row0 + rr) * NN + lane * 8;
            float4 a0 = *(const float4*)ap;
            float4 a1 = *(const float4*)(ap + 4);
            unsigned byte = 0;
            byte |= (a0.x > 0.f) ? 1u : 0u;  byte |= (a0.y > 0.f) ? 2u : 0u;
            byte |= (a0.z > 0.f) ? 4u : 0u;  byte |= (a0.w > 0.f) ? 8u : 0u;
            byte |= (a1.x > 0.f) ? 16u : 0u; byte |= (a1.y > 0.f) ? 32u : 0u;
            byte |= (a1.z > 0.f) ? 64u : 0u; byte |= (a1.w > 0.f) ? 128u : 0u;
            mbB[(size_t)(row0 + rr) * 64 + lane] = (unsigned char)byte;
        }
    } else {
        int gid = (bid - 2048) * 256 + threadIdx.x;
        int c = gid & 511, k = gid >> 9;
        int kb = k >> 5, g = (k >> 3) & 3, e = k & 7;
        wB[(((size_t)(kb * 4 + g) * 512) + c) * 8 + e] = f2bf(w[(size_t)k * 512 + c]);
    }
}

__global__ __launch_bounds__(256) void k_proj(
    const float* __restrict__ x, const unsigned short* __restrict__ wB,
    const float* __restrict__ ai, const float* __restrict__ aj,
    unsigned short* __restrict__ hB, float* __restrict__ ciT, float* __restrict__ cjT)
{
    __shared__ unsigned short hs[NH * 4096];
    const int tid = threadIdx.x;
    const int lane = tid & 63, head = tid >> 6;
    const int l15 = lane & 15, g = lane >> 4;
    const int row0 = blockIdx.x * 32;

    f32x4 acc[2][8] = {};
    const float* xp0 = x + (size_t)(row0 + l15) * INF + g * 8;
    const float* xp1 = xp0 + 16 * INF;
    const unsigned short* bp = wB + ((size_t)g * 512 + head * 128 + l15) * 8;

    #pragma unroll
    for (int kb = 0; kb < 8; ++kb) {
        float4 f0 = *(const float4*)(xp0 + kb * 32);
        float4 f1 = *(const float4*)(xp0 + kb * 32 + 4);
        float4 f2 = *(const float4*)(xp1 + kb * 32);
        float4 f3 = *(const float4*)(xp1 + kb * 32 + 4);
        bf16x8 a0 = pk8(f0, f1);
        bf16x8 a1 = pk8(f2, f3);
        #pragma unroll
        for (int nf = 0; nf < 8; ++nf) {
            bf16x8 bv = *(const bf16x8*)(bp + (size_t)kb * 16384 + nf * 128);
            acc[0][nf] = __builtin_amdgcn_mfma_f32_16x16x32_bf16(a0, bv, acc[0][nf], 0, 0, 0);
            acc[1][nf] = __builtin_amdgcn_mfma_f32_16x16x32_bf16(a1, bv, acc[1][nf], 0, 0, 0);
        }
    }

    float aiv[8], ajv[8];
    #pragma unroll
    for (int nf = 0; nf < 8; ++nf) {
        aiv[nf] = ai[head * 128 + nf * 16 + l15];
        ajv[nf] = aj[head * 128 + nf * 16 + l15];
    }
    const int b = row0 >> 9;
    const int nloc0 = row0 & 511;
    const int kb2 = nloc0 >> 5;

    #pragma unroll
    for (int m = 0; m < 2; ++m) {
        float pi[4] = {0,0,0,0}, pj[4] = {0,0,0,0};
        #pragma unroll
        for (int nf = 0; nf < 8; ++nf)
            #pragma unroll
            for (int reg = 0; reg < 4; ++reg) {
                pi[reg] = fmaf(acc[m][nf][reg], aiv[nf], pi[reg]);
                pj[reg] = fmaf(acc[m][nf][reg], ajv[nf], pj[reg]);
            }
        #pragma unroll
        for (int reg = 0; reg < 4; ++reg) {
            #pragma unroll
            for (int off = 1; off < 16; off <<= 1) {
                pi[reg] += __shfl_xor(pi[reg], off);
                pj[reg] += __shfl_xor(pj[reg], off);
            }
        }
        if (l15 == 0) {
            #pragma unroll
            for (int reg = 0; reg < 4; ++reg) {
                int n = nloc0 + 16 * m + 4 * g + reg;
                ciT[((size_t)(head * BSZ + b) * NN) + n] = pi[reg];
                cjT[((size_t)(head * BSZ + b) * NN) + n] = pj[reg];
            }
        }
        #pragma unroll
        for (int reg = 0; reg < 4; ++reg) {
            int jloc = 16 * m + 4 * g + reg;
            int g2 = jloc >> 3, e = jloc & 7;
            #pragma unroll
            for (int nf = 0; nf < 8; ++nf)
                hs[head * 4096 + nf * 512 + g2 * 128 + l15 * 8 + e] =
                    f2bf(acc[m][nf][reg]);
        }
    }
    __syncthreads();
    {
        ushort8* dst = (ushort8*)(hB + (((size_t)(b * 4 + head) * 16 + kb2) * 4096));
        const ushort8* src = (const ushort8*)(hs + head * 4096);
        #pragma unroll
        for (int it = 0; it < 8; ++it)
            dst[it * 64 + lane] = src[it * 64 + lane];
    }
}

__global__ __launch_bounds__(256, 4) void k_attn(
    const unsigned short* __restrict__ hB, const float* __restrict__ ciT,
    const float* __restrict__ cjT, const unsigned* __restrict__ mb,
    const float* __restrict__ bias, float* __restrict__ out)
{
    __shared__ __align__(16) unsigned short Bst[2][4096];
    __shared__ __align__(16) float cjh[NN];
    __shared__ float cih[64];
    __shared__ unsigned maskS[64][17];
    __shared__ float Mpart[4];

    const int tid = threadIdx.x;
    const int lane = tid & 63, wave = tid >> 6;
    const int l15 = lane & 15, g = lane >> 4;

    const int orig = blockIdx.x;
    const int swz = (orig & 7) * 128 + (orig >> 3);
    const int b  = swz >> 5;
    const int h  = (swz >> 3) & 3;
    const int i0 = (swz & 7) * 64;

    const char* gslab = (const char*)(hB + (size_t)(b * NH + h) * 65536);

    gl_lds16(gslab + wave * 2048 + lane * 16,        (char*)&Bst[0][0] + wave * 2048);
    gl_lds16(gslab + wave * 2048 + 1024 + lane * 16, (char*)&Bst[0][0] + wave * 2048 + 1024);

    {
        const float* src = cjT + (size_t)(h * BSZ + b) * NN;
        float v0 = src[tid], v1 = src[tid + 256];
        cjh[tid] = v0; cjh[tid + 256] = v1;
        float mv = fmaxf(v0, v1);
        #pragma unroll
        for (int off = 32; off; off >>= 1) mv = fmaxf(mv, __shfl_xor(mv, off));
        if (lane == 0) Mpart[wave] = mv;
        if (tid < 64) cih[tid] = ciT[(size_t)(h * BSZ + b) * NN + i0 + tid];
        uint4 m4 = ((const uint4*)(mb + ((size_t)b * NN + i0) * 16))[tid];
        int base = tid * 4, row = base >> 4, wi = base & 15;
        maskS[row][wi] = m4.x; maskS[row][wi + 1] = m4.y;
        maskS[row][wi + 2] = m4.z; maskS[row][wi + 3] = m4.w;
    }
    __syncthreads();

    const float M = fmaxf(fmaxf(Mpart[0], Mpart[1]), fmaxf(Mpart[2], Mpart[3]));
    const float bc = cih[wave * 16 + l15];
    float smx = bc + M;
    const float mrow = fmaxf(smx, NEG_SLOPE * smx);

    float bvv[8];
    #pragma unroll
    for (int nf = 0; nf < 8; ++nf) bvv[nf] = bias[h * 128 + nf * 16 + l15];

    bf16x8 ones;
    #pragma unroll
    for (int e = 0; e < 8; ++e) ones[e] = (short)0x3F80;

    f32x4 acc[8] = {};
    f32x4 accs = {};
    int cur = 0;
    const unsigned* mrowp = maskS[wave * 16 + l15];

    for (int kb = 0; kb < 16; ++kb) {
        if (kb < 15) {
            const char* gs = gslab + (size_t)(kb + 1) * 8192 + wave * 2048 + lane * 16;
            char* ld = (char*)&Bst[cur ^ 1][0] + wave * 2048;
            gl_lds16(gs, ld);
            gl_lds16(gs + 1024, ld + 1024);
        }

        float4 cva = *(const float4*)&cjh[kb * 32 + g * 8];
        float4 cvb = *(const float4*)&cjh[kb * 32 + g * 8 + 4];
        float cj8[8] = {cva.x, cva.y, cva.z, cva.w, cvb.x, cvb.y, cvb.z, cvb.w};
        unsigned byte = (mrowp[kb] >> (g * 8)) & 0xFFu;
        float p[8];
        #pragma unroll
        for (int e = 0; e < 8; ++e) {
            float s = bc + cj8[e];
            s = fmaxf(s, NEG_SLOPE * s);
            float pe = __expf(s - mrow);
            p[e] = ((byte >> e) & 1u) ? pe : 0.f;
        }
        unsigned d0, d1, d2, d3;
        asm("v_cvt_pk_bf16_f32 %0, %1, %2" : "=v"(d0) : "v"(p[0]), "v"(p[1]));
        asm("v_cvt_pk_bf16_f32 %0, %1, %2" : "=v"(d1) : "v"(p[2]), "v"(p[3]));
        asm("v_cvt_pk_bf16_f32 %0, %1, %2" : "=v"(d2) : "v"(p[4]), "v"(p[5]));
        asm("v_cvt_pk_bf16_f32 %0, %1, %2" : "=v"(d3) : "v"(p[6]), "v"(p[7]));
        uint4 u; u.x = d0; u.y = d1; u.z = d2; u.w = d3;
        bf16x8 av = __builtin_bit_cast(bf16x8, u);

        const char* bb = (const char*)&Bst[cur][0] + lane * 16;
        bf16x8 bfr[8];
        #pragma unroll
        for (int nf = 0; nf < 8; ++nf)
            bfr[nf] = *(const bf16x8*)(bb + nf * 1024);

        #pragma unroll
        for (int nf = 0; nf < 8; ++nf)
            acc[nf] = __builtin_amdgcn_mfma_f32_16x16x32_bf16(av, bfr[nf], acc[nf], 0, 0, 0);
        accs = __builtin_amdgcn_mfma_f32_16x16x32_bf16(av, ones, accs, 0, 0, 0);

        if (kb < 15) { __syncthreads(); cur ^= 1; }
    }

    #pragma unroll
    for (int reg = 0; reg < 4; ++reg) {
        float sum = accs[reg];
        float inv = sum > 0.f ? 1.f / sum : 0.f;
        const int i = i0 + wave * 16 + g * 4 + reg;
        #pragma unroll
        for (int nf = 0; nf < 8; ++nf) {
            int colg = h * 128 + nf * 16 + l15;
            out[(size_t)(b * NN + i) * HD + colg] = acc[nf][reg] * inv + bvv[nf];
        }
    }
}

extern "C" void kernel_launch(void* const* d_in, const int* in_sizes, int n_in,
                              void* d_out, int out_size, void* d_ws, size_t ws_size,
                              hipStream_t stream)
{
    const float* x    = (const float*)d_in[0];
    const float* adj  = (const float*)d_in[1];
    const float* w    = (const float*)d_in[2];
    const float* ai   = (const float*)d_in[3];
    const float* aj   = (const float*)d_in[4];
    const float* bias = (const float*)d_in[5];
    float* out = (float*)d_out;

    char* ws = (char*)d_ws;
    unsigned short* wB = (unsigned short*)ws;                       //   262,144 B
    unsigned short* hB = (unsigned short*)(ws + 262144);            // 16,777,216 B
    float* ciT         = (float*)(ws + 17039360);                   //   262,144 B
    float* cjT         = (float*)(ws + 17301504);                   //   262,144 B
    unsigned char* mbB = (unsigned char*)(ws + 17563648);           // 1,048,576 B
    unsigned* flags    = (unsigned*)(ws + 18612224);                //       256 B

    hipMemsetAsync(flags, 0, 256, stream);   // zero dependency counters per call

    int maxB = 0;
    hipError_t e = hipOccupancyMaxActiveBlocksPerMultiprocessor(
        &maxB, (const void*)mega2, 256, 0);
    if (e == hipSuccess && maxB >= 4) {
        void* args[] = {(void*)&x, (void*)&adj, (void*)&w, (void*)&ai, (void*)&aj,
                        (void*)&bias, (void*)&out, (void*)&wB, (void*)&hB,
                        (void*)&ciT, (void*)&cjT, (void*)&mbB, (void*)&flags};
        hipLaunchCooperativeKernel((const void*)mega2, dim3(1024), dim3(256),
                                   args, 0, stream);
    } else {
        k_prep<<<2560, 256, 0, stream>>>(w, wB, adj, mbB);
        k_proj<<<BSZ * NN / 32, 256, 0, stream>>>(x, wB, ai, aj, hB, ciT, cjT);
        k_attn<<<BSZ * NH * (NN / 64), 256, 0, stream>>>(hB, ciT, cjT,
                                                         (const unsigned*)mbB, bias, out);
    }
}

// Round 16
// 49.638 us; speedup vs baseline: 1.1058x; 1.1058x over previous
//
#include <hip/hip_runtime.h>

#define BSZ 32
#define NN 512
#define INF 256
#define NH 4
#define HD 512
#define NEG_SLOPE 0.2f

typedef __attribute__((ext_vector_type(8))) short bf16x8;
typedef __attribute__((ext_vector_type(8))) unsigned short ushort8;
typedef __attribute__((ext_vector_type(4))) float f32x4;

static __device__ __forceinline__ unsigned short f2bf(float f) {
    unsigned u = __builtin_bit_cast(unsigned, f);
    return (unsigned short)((u + 0x7FFFu + ((u >> 16) & 1u)) >> 16);
}

static __device__ __forceinline__ bf16x8 pk8(float4 a, float4 b) {
    unsigned d0, d1, d2, d3;
    asm("v_cvt_pk_bf16_f32 %0, %1, %2" : "=v"(d0) : "v"(a.x), "v"(a.y));
    asm("v_cvt_pk_bf16_f32 %0, %1, %2" : "=v"(d1) : "v"(a.z), "v"(a.w));
    asm("v_cvt_pk_bf16_f32 %0, %1, %2" : "=v"(d2) : "v"(b.x), "v"(b.y));
    asm("v_cvt_pk_bf16_f32 %0, %1, %2" : "=v"(d3) : "v"(b.z), "v"(b.w));
    uint4 u; u.x = d0; u.y = d1; u.z = d2; u.w = d3;
    return __builtin_bit_cast(bf16x8, u);
}

static __device__ __forceinline__ void gl_lds16(const void* g, void* l) {
    __builtin_amdgcn_global_load_lds(
        (const __attribute__((address_space(1))) unsigned int*)g,
        (__attribute__((address_space(3))) unsigned int*)l, 16, 0, 0);
}

// ---- fused prologue: blocks [0,2048) adj->maskbytes; [2048,2560) w-pack ----
__global__ __launch_bounds__(256) void k_prep(
    const float* __restrict__ w, unsigned short* __restrict__ wB,
    const float* __restrict__ adj, unsigned char* __restrict__ mbB)
{
    const int bid = blockIdx.x;
    if (bid < 2048) {
        const int lane = threadIdx.x & 63, wave = threadIdx.x >> 6;
        const int row0 = bid * 8 + wave * 2;
        #pragma unroll
        for (int rr = 0; rr < 2; ++rr) {
            const float* ap = adj + (size_t)(row0 + rr) * NN + lane * 8;
            float4 a0 = *(const float4*)ap;
            float4 a1 = *(const float4*)(ap + 4);
            unsigned byte = 0;
            byte |= (a0.x > 0.f) ? 1u : 0u;  byte |= (a0.y > 0.f) ? 2u : 0u;
            byte |= (a0.z > 0.f) ? 4u : 0u;  byte |= (a0.w > 0.f) ? 8u : 0u;
            byte |= (a1.x > 0.f) ? 16u : 0u; byte |= (a1.y > 0.f) ? 32u : 0u;
            byte |= (a1.z > 0.f) ? 64u : 0u; byte |= (a1.w > 0.f) ? 128u : 0u;
            mbB[(size_t)(row0 + rr) * 64 + lane] = (unsigned char)byte;
        }
    } else {
        int gid = (bid - 2048) * 256 + threadIdx.x;
        int c = gid & 511, k = gid >> 9;
        int kb = k >> 5, g = (k >> 3) & 3, e = k & 7;
        wB[(((size_t)(kb * 4 + g) * 512) + c) * 8 + e] = f2bf(w[(size_t)k * 512 + c]);
    }
}

// ---- projection GEMM (unchanged R13): 32 rows/block, 512 blocks ----
__global__ __launch_bounds__(256) void k_proj(
    const float* __restrict__ x, const unsigned short* __restrict__ wB,
    const float* __restrict__ ai, const float* __restrict__ aj,
    unsigned short* __restrict__ hB, float* __restrict__ ciT, float* __restrict__ cjT)
{
    __shared__ unsigned short hs[NH * 4096];
    const int tid = threadIdx.x;
    const int lane = tid & 63, head = tid >> 6;
    const int l15 = lane & 15, g = lane >> 4;
    const int row0 = blockIdx.x * 32;

    f32x4 acc[2][8] = {};
    const float* xp0 = x + (size_t)(row0 + l15) * INF + g * 8;
    const float* xp1 = xp0 + 16 * INF;
    const unsigned short* bp = wB + ((size_t)g * 512 + head * 128 + l15) * 8;

    #pragma unroll
    for (int kb = 0; kb < 8; ++kb) {
        float4 f0 = *(const float4*)(xp0 + kb * 32);
        float4 f1 = *(const float4*)(xp0 + kb * 32 + 4);
        float4 f2 = *(const float4*)(xp1 + kb * 32);
        float4 f3 = *(const float4*)(xp1 + kb * 32 + 4);
        bf16x8 a0 = pk8(f0, f1);
        bf16x8 a1 = pk8(f2, f3);
        #pragma unroll
        for (int nf = 0; nf < 8; ++nf) {
            bf16x8 bv = *(const bf16x8*)(bp + (size_t)kb * 16384 + nf * 128);
            acc[0][nf] = __builtin_amdgcn_mfma_f32_16x16x32_bf16(a0, bv, acc[0][nf], 0, 0, 0);
            acc[1][nf] = __builtin_amdgcn_mfma_f32_16x16x32_bf16(a1, bv, acc[1][nf], 0, 0, 0);
        }
    }

    float aiv[8], ajv[8];
    #pragma unroll
    for (int nf = 0; nf < 8; ++nf) {
        aiv[nf] = ai[head * 128 + nf * 16 + l15];
        ajv[nf] = aj[head * 128 + nf * 16 + l15];
    }
    const int b = row0 >> 9;
    const int nloc0 = row0 & 511;
    const int kb2 = nloc0 >> 5;

    #pragma unroll
    for (int m = 0; m < 2; ++m) {
        float pi[4] = {0,0,0,0}, pj[4] = {0,0,0,0};
        #pragma unroll
        for (int nf = 0; nf < 8; ++nf)
            #pragma unroll
            for (int reg = 0; reg < 4; ++reg) {
                pi[reg] = fmaf(acc[m][nf][reg], aiv[nf], pi[reg]);
                pj[reg] = fmaf(acc[m][nf][reg], ajv[nf], pj[reg]);
            }
        #pragma unroll
        for (int reg = 0; reg < 4; ++reg) {
            #pragma unroll
            for (int off = 1; off < 16; off <<= 1) {
                pi[reg] += __shfl_xor(pi[reg], off);
                pj[reg] += __shfl_xor(pj[reg], off);
            }
        }
        if (l15 == 0) {
            #pragma unroll
            for (int reg = 0; reg < 4; ++reg) {
                int n = nloc0 + 16 * m + 4 * g + reg;
                ciT[((size_t)(head * BSZ + b) * NN) + n] = pi[reg];
                cjT[((size_t)(head * BSZ + b) * NN) + n] = pj[reg];
            }
        }
        #pragma unroll
        for (int reg = 0; reg < 4; ++reg) {
            int jloc = 16 * m + 4 * g + reg;
            int g2 = jloc >> 3, e = jloc & 7;
            #pragma unroll
            for (int nf = 0; nf < 8; ++nf)
                hs[head * 4096 + nf * 512 + g2 * 128 + l15 * 8 + e] =
                    f2bf(acc[m][nf][reg]);
        }
    }
    __syncthreads();
    {
        ushort8* dst = (ushort8*)(hB + (((size_t)(b * 4 + head) * 16 + kb2) * 4096));
        const ushort8* src = (const ushort8*)(hs + head * 4096);
        #pragma unroll
        for (int it = 0; it < 8; ++it)
            dst[it * 64 + lane] = src[it * 64 + lane];
    }
}

// ---- fused attention, T3/T4: 4-slab ring, 3-deep prefetch, COUNTED vmcnt ----
// Per kb: waitcnt vmcnt(4) [own kb loads done; kb+1/kb+2 in flight] -> raw
// s_barrier -> sched fence -> stage(kb+3) -> MFMA(kb). Never vmcnt(0) in loop.
__global__ __launch_bounds__(256, 4) void k_attn(
    const unsigned short* __restrict__ hB, const float* __restrict__ ciT,
    const float* __restrict__ cjT, const unsigned* __restrict__ mb,
    const float* __restrict__ bias, float* __restrict__ out)
{
    __shared__ __align__(16) unsigned short Bst[4][4096];  // 32 KB, 4-slab ring
    __shared__ __align__(16) float cjh[NN];                // 2 KB
    __shared__ float cih[64];
    __shared__ unsigned maskS[64][17];                     // 4.25 KB, padded
    __shared__ float Mpart[4];

    const int tid = threadIdx.x;
    const int lane = tid & 63, wave = tid >> 6;
    const int l15 = lane & 15, g = lane >> 4;

    const int orig = blockIdx.x;                    // 1024 blocks, bijective
    const int swz = (orig & 7) * 128 + (orig >> 3); // XCD x -> b in {4x..4x+3}
    const int b  = swz >> 5;
    const int h  = (swz >> 3) & 3;
    const int i0 = (swz & 7) * 64;

    const char* gslab = (const char*)(hB + (size_t)(b * NH + h) * 65536);

    // prefetch slabs 0..2 (drained by the setup __syncthreads; pipeline
    // refills via in-loop stages of 3,4,5)
    #pragma unroll
    for (int s = 0; s < 3; ++s) {
        const char* gs = gslab + (size_t)s * 8192 + wave * 2048 + lane * 16;
        char* ld = (char*)&Bst[s][0] + wave * 2048;
        gl_lds16(gs, ld);
        gl_lds16(gs + 1024, ld + 1024);
    }

    {   // cj -> LDS + unmasked max (stabilizer upper bound); masks; ci
        const float* src = cjT + (size_t)(h * BSZ + b) * NN;
        float v0 = src[tid], v1 = src[tid + 256];
        cjh[tid] = v0; cjh[tid + 256] = v1;
        float mv = fmaxf(v0, v1);
        #pragma unroll
        for (int off = 32; off; off >>= 1) mv = fmaxf(mv, __shfl_xor(mv, off));
        if (lane == 0) Mpart[wave] = mv;
        if (tid < 64) cih[tid] = ciT[(size_t)(h * BSZ + b) * NN + i0 + tid];
        uint4 m4 = ((const uint4*)(mb + ((size_t)b * NN + i0) * 16))[tid];
        int base = tid * 4, row = base >> 4, wi = base & 15;
        maskS[row][wi] = m4.x; maskS[row][wi + 1] = m4.y;
        maskS[row][wi + 2] = m4.z; maskS[row][wi + 3] = m4.w;
    }
    __syncthreads();   // single full drain (setup + slabs 0-2)

    const float M = fmaxf(fmaxf(Mpart[0], Mpart[1]), fmaxf(Mpart[2], Mpart[3]));
    const float bc = cih[wave * 16 + l15];
    float smx = bc + M;
    const float mrow = fmaxf(smx, NEG_SLOPE * smx);

    float bvv[8];
    #pragma unroll
    for (int nf = 0; nf < 8; ++nf) bvv[nf] = bias[h * 128 + nf * 16 + l15];

    bf16x8 ones;
    #pragma unroll
    for (int e = 0; e < 8; ++e) ones[e] = (short)0x3F80;

    f32x4 acc[8] = {};
    f32x4 accs = {};
    const unsigned* mrowp = maskS[wave * 16 + l15];

    #pragma unroll
    for (int kb = 0; kb < 16; ++kb) {
        // counted wait: own loads for slab kb retired; newer slabs in flight
        const int rem = 15 - kb;
        if (rem >= 2)      asm volatile("s_waitcnt vmcnt(4)" ::: "memory");
        else if (rem == 1) asm volatile("s_waitcnt vmcnt(2)" ::: "memory");
        else               asm volatile("s_waitcnt vmcnt(0)" ::: "memory");
        __builtin_amdgcn_s_barrier();          // raw barrier, no drain
        __builtin_amdgcn_sched_barrier(0);     // fence (rule #18)

        if (kb + 3 < 16) {   // stage slab kb+3 into ring slot (kb+3)&3
            const char* gs = gslab + (size_t)(kb + 3) * 8192 + wave * 2048 + lane * 16;
            char* ld = (char*)&Bst[(kb + 3) & 3][0] + wave * 2048;
            gl_lds16(gs, ld);
            gl_lds16(gs + 1024, ld + 1024);
        }

        // A-frag synthesis
        float4 cva = *(const float4*)&cjh[kb * 32 + g * 8];
        float4 cvb = *(const float4*)&cjh[kb * 32 + g * 8 + 4];
        float cj8[8] = {cva.x, cva.y, cva.z, cva.w, cvb.x, cvb.y, cvb.z, cvb.w};
        unsigned byte = (mrowp[kb] >> (g * 8)) & 0xFFu;
        float p[8];
        #pragma unroll
        for (int e = 0; e < 8; ++e) {
            float s = bc + cj8[e];
            s = fmaxf(s, NEG_SLOPE * s);
            float pe = __expf(s - mrow);
            p[e] = ((byte >> e) & 1u) ? pe : 0.f;
        }
        unsigned d0, d1, d2, d3;
        asm("v_cvt_pk_bf16_f32 %0, %1, %2" : "=v"(d0) : "v"(p[0]), "v"(p[1]));
        asm("v_cvt_pk_bf16_f32 %0, %1, %2" : "=v"(d1) : "v"(p[2]), "v"(p[3]));
        asm("v_cvt_pk_bf16_f32 %0, %1, %2" : "=v"(d2) : "v"(p[4]), "v"(p[5]));
        asm("v_cvt_pk_bf16_f32 %0, %1, %2" : "=v"(d3) : "v"(p[6]), "v"(p[7]));
        uint4 u; u.x = d0; u.y = d1; u.z = d2; u.w = d3;
        bf16x8 av = __builtin_bit_cast(bf16x8, u);

        // B-frags from ring slot kb&3
        const char* bb = (const char*)&Bst[kb & 3][0] + lane * 16;
        bf16x8 bfr[8];
        #pragma unroll
        for (int nf = 0; nf < 8; ++nf)
            bfr[nf] = *(const bf16x8*)(bb + nf * 1024);

        #pragma unroll
        for (int nf = 0; nf < 8; ++nf)
            acc[nf] = __builtin_amdgcn_mfma_f32_16x16x32_bf16(av, bfr[nf], acc[nf], 0, 0, 0);
        accs = __builtin_amdgcn_mfma_f32_16x16x32_bf16(av, ones, accs, 0, 0, 0);
    }

    #pragma unroll
    for (int reg = 0; reg < 4; ++reg) {
        float sum = accs[reg];
        float inv = sum > 0.f ? 1.f / sum : 0.f;
        const int i = i0 + wave * 16 + g * 4 + reg;
        #pragma unroll
        for (int nf = 0; nf < 8; ++nf) {
            int colg = h * 128 + nf * 16 + l15;
            out[(size_t)(b * NN + i) * HD + colg] = acc[nf][reg] * inv + bvv[nf];
        }
    }
}

extern "C" void kernel_launch(void* const* d_in, const int* in_sizes, int n_in,
                              void* d_out, int out_size, void* d_ws, size_t ws_size,
                              hipStream_t stream)
{
    const float* x    = (const float*)d_in[0];
    const float* adj  = (const float*)d_in[1];
    const float* w    = (const float*)d_in[2];
    const float* ai   = (const float*)d_in[3];
    const float* aj   = (const float*)d_in[4];
    const float* bias = (const float*)d_in[5];
    float* out = (float*)d_out;

    char* ws = (char*)d_ws;
    unsigned short* wB = (unsigned short*)ws;                       //   262,144 B
    unsigned short* hB = (unsigned short*)(ws + 262144);            // 16,777,216 B
    float* ciT         = (float*)(ws + 17039360);                   //   262,144 B
    float* cjT         = (float*)(ws + 17301504);                   //   262,144 B
    unsigned char* mbB = (unsigned char*)(ws + 17563648);           // 1,048,576 B

    k_prep<<<2560, 256, 0, stream>>>(w, wB, adj, mbB);
    k_proj<<<BSZ * NN / 32, 256, 0, stream>>>(x, wB, ai, aj, hB, ciT, cjT);
    k_attn<<<BSZ * NH * (NN / 64), 256, 0, stream>>>(hB, ciT, cjT,
                                                     (const unsigned*)mbB, bias, out);
}